// Round 8
// baseline (515.960 us; speedup 1.0000x reference)
//
#include <hip/hip_runtime.h>
#include <hip/hip_bf16.h>

#define NS 2048
#define NC 4096
#define SD 1024
#define BD 512
#define NH 8
#define DK 128
#define CSPLIT 4

typedef __bf16 bf16;
typedef __bf16 bf16x8 __attribute__((ext_vector_type(8)));
typedef __bf16 bf16x4 __attribute__((ext_vector_type(4)));
typedef float f32x4 __attribute__((ext_vector_type(4)));
typedef unsigned u32x4 __attribute__((ext_vector_type(4)));

__device__ __forceinline__ bf16 f2bf(float f) { return (bf16)f; }
__device__ __forceinline__ bf16x8 ld8(const bf16* p) { return *(const bf16x8*)p; }
__device__ __forceinline__ f32x4 mfma16(bf16x8 a, bf16x8 b, f32x4 c) {
  return __builtin_amdgcn_mfma_f32_16x16x32_bf16(a, b, c, 0, 0, 0);
}
__device__ __forceinline__ unsigned pkbf(float lo, float hi) {
  unsigned short a = __builtin_bit_cast(unsigned short, (bf16)lo);
  unsigned short b = __builtin_bit_cast(unsigned short, (bf16)hi);
  return (unsigned)a | ((unsigned)b << 16);
}

// ---------------- fused cast f32 -> bf16 for all 7 tensors ----------------
__global__ void k_cast_all(const float* __restrict__ HS, const float* __restrict__ HC,
                           const float* __restrict__ WQ, const float* __restrict__ WK,
                           const float* __restrict__ WV, const float* __restrict__ WO,
                           const float* __restrict__ G,
                           bf16* __restrict__ HSb, bf16* __restrict__ HCb,
                           bf16* __restrict__ WQb, bf16* __restrict__ WKb,
                           bf16* __restrict__ WVb, bf16* __restrict__ WOb,
                           bf16* __restrict__ Gb) {
  const int n0 = NS * SD / 4, n1 = NC * BD / 4, n2 = SD * SD / 4, n3 = SD * BD / 4;
  const int n4 = SD * BD / 4, n5 = SD * SD / 4, n6 = NS * NC / 4;
  const int total = n0 + n1 + n2 + n3 + n4 + n5 + n6;
  int i = blockIdx.x * blockDim.x + threadIdx.x;
  const int stride = gridDim.x * blockDim.x;
  for (; i < total; i += stride) {
    const float* s; bf16* d; int off = i;
    if (off < n0) { s = HS; d = HSb; }
    else { off -= n0;
      if (off < n1) { s = HC; d = HCb; }
      else { off -= n1;
        if (off < n2) { s = WQ; d = WQb; }
        else { off -= n2;
          if (off < n3) { s = WK; d = WKb; }
          else { off -= n3;
            if (off < n4) { s = WV; d = WVb; }
            else { off -= n4;
              if (off < n5) { s = WO; d = WOb; }
              else { off -= n5; s = G; d = Gb; }
            }
          }
        }
      }
    }
    float4 v = ((const float4*)s)[off];
    bf16x4 o;
    o[0] = f2bf(v.x); o[1] = f2bf(v.y); o[2] = f2bf(v.z); o[3] = f2bf(v.w);
    ((bf16x4*)d)[off] = o;
  }
}

// ---------------- GEMM 64x64 tile: C[m][n] = sum_k A[m][k]*B[n][k] ----------------
template <typename CT>
__global__ __launch_bounds__(256) void k_gemm64(const bf16* __restrict__ A,
                                                const bf16* __restrict__ B,
                                                CT* __restrict__ C,
                                                int M, int N, int K) {
  __shared__ bf16 As[64 * 64];
  __shared__ bf16 Bs[64 * 64];
  const int tid = threadIdx.x;
  const int l = tid & 63, w = tid >> 6;
  const int g = l >> 4, r15 = l & 15;
  const int m0 = blockIdx.y * 64, n0 = blockIdx.x * 64;
  const int wm = (w >> 1) * 32, wn = (w & 1) * 32;
  f32x4 acc[2][2] = {};
  for (int k0 = 0; k0 < K; k0 += 64) {
    __syncthreads();
#pragma unroll
    for (int i = 0; i < 2; i++) {
      int slot = tid + i * 256;
      int row = slot >> 3, cp = slot & 7;
      int gc = cp ^ (row & 7);
      *(uint4*)(As + slot * 8) = *(const uint4*)(A + (size_t)(m0 + row) * K + k0 + gc * 8);
    }
#pragma unroll
    for (int i = 0; i < 2; i++) {
      int slot = tid + i * 256;
      int row = slot >> 3, cp = slot & 7;
      int gc = cp ^ (row & 7);
      *(uint4*)(Bs + slot * 8) = *(const uint4*)(B + (size_t)(n0 + row) * K + k0 + gc * 8);
    }
    __syncthreads();
#pragma unroll
    for (int kk = 0; kk < 2; kk++) {
      bf16x8 af[2], bfr[2];
#pragma unroll
      for (int mi = 0; mi < 2; mi++) {
        int row = wm + mi * 16 + r15;
        int cidx = (kk * 4 + g) ^ (row & 7);
        af[mi] = *(const bf16x8*)(As + row * 64 + cidx * 8);
      }
#pragma unroll
      for (int ni = 0; ni < 2; ni++) {
        int row = wn + ni * 16 + r15;
        int cidx = (kk * 4 + g) ^ (row & 7);
        bfr[ni] = *(const bf16x8*)(Bs + row * 64 + cidx * 8);
      }
#pragma unroll
      for (int mi = 0; mi < 2; mi++)
#pragma unroll
        for (int ni = 0; ni < 2; ni++)
          acc[mi][ni] = mfma16(af[mi], bfr[ni], acc[mi][ni]);
    }
  }
#pragma unroll
  for (int mi = 0; mi < 2; mi++)
#pragma unroll
    for (int ni = 0; ni < 2; ni++)
#pragma unroll
      for (int rr = 0; rr < 4; rr++) {
        int mrow = m0 + wm + mi * 16 + g * 4 + rr;
        int ncol = n0 + wn + ni * 16 + r15;
        float v = acc[mi][ni][rr];
        if constexpr (sizeof(CT) == 4) C[(size_t)mrow * N + ncol] = v;
        else                           C[(size_t)mrow * N + ncol] = f2bf(v);
      }
}

// ---------------- transpose V (NC x SD) -> Vt (SD x NC) ----------------
__global__ __launch_bounds__(256) void k_transpose(const bf16* __restrict__ V, bf16* __restrict__ Vt) {
  __shared__ bf16 tile[32][33];
  const int t = threadIdx.x;
  const int col = t & 31, r0 = t >> 5;
  const int cbase = blockIdx.y * 32;
  const int dbase = blockIdx.x * 32;
#pragma unroll
  for (int i = 0; i < 4; i++) {
    int r = r0 + i * 8;
    tile[r][col] = V[(size_t)(cbase + r) * SD + dbase + col];
  }
  __syncthreads();
#pragma unroll
  for (int i = 0; i < 4; i++) {
    int r = r0 + i * 8;
    Vt[(size_t)(dbase + r) * NC + cbase + col] = tile[col][r];
  }
}

// ---------------- fused gated attention v3 ----------------
// grid (NS/64, NH, CSPLIT) = 1024 blocks -> 4 blocks/CU. Wave owns 16 s-rows.
// No P-LDS round trip: in-register bf16 pack + shfl_xor butterfly builds the
// PV B-fragment (target lane g' = (csub<<1)|(g>>1)). Gate is bf16, one 8B load
// per subtile. Epilogue transposes O through LDS for coalesced 16B stores.
__global__ __launch_bounds__(256, 4) void k_attn3(const bf16* __restrict__ Q, const bf16* __restrict__ Km,
                                                  const bf16* __restrict__ Vt, const bf16* __restrict__ Gb,
                                                  float* __restrict__ psum_part, bf16* __restrict__ Opart) {
  __shared__ bf16 Kl[64 * 128];   // 16 KB, rows 256B = 16 x 16B slots, XOR-swizzled
  __shared__ bf16 Vl[128 * 64];   // 16 KB, rows 128B = 8 x 16B slots, XOR-swizzled
  const int tid = threadIdx.x, l = tid & 63, w = tid >> 6, g = l >> 4, r15 = l & 15;
  const int s0 = blockIdx.x * 64;
  const int h = blockIdx.y, hoff = h * DK;
  const int ch = blockIdx.z, cbase = ch * (NC / CSPLIT);
  const int srow = s0 + w * 16 + r15;
  const float scale = 0.08838834764831845f;  // 1/sqrt(128)
  char* KlB = (char*)Kl;
  char* VlB = (char*)Vl;
  const int swz = r15 & 7;

  bf16x8 qf[4];
#pragma unroll
  for (int kk = 0; kk < 4; kk++)
    qf[kk] = ld8(Q + (size_t)srow * SD + hoff + kk * 32 + g * 8);

  f32x4 oacc[8] = {};
  float psum = 0.f;

  const int krow0 = tid >> 4, ksl = tid & 15;  // K: 64 rows x 16 slots
  const int vrow0 = tid >> 3, vsl = tid & 7;   // V: 128 rows x 8 slots
  uint4 kreg[4], vreg[4];
  auto loadstep = [&](int cb) {
#pragma unroll
    for (int i = 0; i < 4; i++)
      kreg[i] = *(const uint4*)(Km + (size_t)(cb + krow0 + i * 16) * SD + hoff + ksl * 8);
#pragma unroll
    for (int i = 0; i < 4; i++)
      vreg[i] = *(const uint4*)(Vt + (size_t)(hoff + vrow0 + i * 32) * NC + cb + vsl * 8);
  };
  loadstep(cbase);

  const int NT = NC / CSPLIT / 64;  // 16
  for (int t = 0; t < NT; ++t) {
    const int cb = cbase + t * 64;
    __syncthreads();
#pragma unroll
    for (int i = 0; i < 4; i++) {
      int row = krow0 + i * 16;
      *(uint4*)(KlB + row * 256 + ((ksl ^ (row & 7)) << 4)) = kreg[i];
    }
#pragma unroll
    for (int i = 0; i < 4; i++) {
      int row = vrow0 + i * 32;
      *(uint4*)(VlB + row * 128 + ((vsl ^ (row & 7)) << 4)) = vreg[i];
    }
    __syncthreads();
    uint2 gcur[4];
#pragma unroll
    for (int cs = 0; cs < 4; cs++)
      gcur[cs] = *(const uint2*)(Gb + (size_t)srow * NC + cb + cs * 16 + g * 4);
    if (t < NT - 1) loadstep(cb + 64);
#pragma unroll
    for (int kc = 0; kc < 2; ++kc) {
      unsigned va0, va1, vb0, vb1;
#pragma unroll
      for (int cs2 = 0; cs2 < 2; ++cs2) {
        const int csub = kc * 2 + cs2;
        bf16x8 kf[4];
#pragma unroll
        for (int kk = 0; kk < 4; kk++)
          kf[kk] = *(const bf16x8*)(KlB + (csub * 16 + r15) * 256 + (((kk * 4 + g) ^ swz) << 4));
        f32x4 a = {0.f, 0.f, 0.f, 0.f};
#pragma unroll
        for (int kk = 0; kk < 4; kk++) a = mfma16(kf[kk], qf[kk], a);
        bf16x4 gb4 = __builtin_bit_cast(bf16x4, gcur[csub]);
        float p0 = __expf(a[0] * scale * (float)gb4[0]);
        float p1 = __expf(a[1] * scale * (float)gb4[1]);
        float p2 = __expf(a[2] * scale * (float)gb4[2]);
        float p3 = __expf(a[3] * scale * (float)gb4[3]);
        psum += (p0 + p1) + (p2 + p3);
        if (cs2 == 0) { va0 = pkbf(p0, p1); va1 = pkbf(p2, p3); }
        else          { vb0 = pkbf(p0, p1); vb1 = pkbf(p2, p3); }
      }
      // butterfly: round 1 (lane ^ 32), round 2 (lane ^ 16)
      const bool glow = (g < 2);
      unsigned sa = glow ? vb0 : va0, sb = glow ? vb1 : va1;
      unsigned e0 = (unsigned)__shfl_xor((int)sa, 32);
      unsigned e1 = (unsigned)__shfl_xor((int)sb, 32);
      unsigned p00 = glow ? va0 : e0, p01 = glow ? va1 : e1;  // slot0 pair
      unsigned p10 = glow ? e0 : vb0, p11 = glow ? e1 : vb1;  // slot1 pair
      const bool ge = ((g & 1) == 0);
      unsigned t0 = ge ? p10 : p00, t1 = ge ? p11 : p01;
      unsigned f0e = (unsigned)__shfl_xor((int)t0, 16);
      unsigned f1e = (unsigned)__shfl_xor((int)t1, 16);
      u32x4 fv;
      fv[0] = ge ? p00 : f0e;
      fv[1] = ge ? p01 : f1e;
      fv[2] = ge ? f0e : p10;
      fv[3] = ge ? f1e : p11;
      bf16x8 pf = __builtin_bit_cast(bf16x8, fv);
#pragma unroll
      for (int nf = 0; nf < 8; ++nf) {
        bf16x8 vf = *(const bf16x8*)(VlB + (nf * 16 + r15) * 128 + (((kc * 4 + g) ^ swz) << 4));
        oacc[nf] = mfma16(vf, pf, oacc[nf]);
      }
    }
  }
  // psum: reduce over the 4 g-groups sharing each s-row
  float ps = psum;
  ps += __shfl_xor(ps, 16);
  ps += __shfl_xor(ps, 32);
  if (g == 0) psum_part[((size_t)ch * NS + srow) * NH + h] = ps;

  // O epilogue: bf16 pack -> swizzled LDS transpose -> coalesced 16B stores
  __syncthreads();
  char* Sw = KlB + w * 4096;  // 4 KB per wave: [16 s][128 d] bf16, swizzled
#pragma unroll
  for (int nf = 0; nf < 8; ++nf) {
    uint2 pk2;
    pk2.x = pkbf(oacc[nf][0], oacc[nf][1]);
    pk2.y = pkbf(oacc[nf][2], oacc[nf][3]);
    *(uint2*)(Sw + r15 * 256 + ((nf * 32 + g * 8) ^ (swz << 4))) = pk2;
  }
  __syncthreads();
  const int sr = l >> 2;
#pragma unroll
  for (int p = 0; p < 4; ++p) {
    int cc = (l & 3) + p * 4;
    uint4 v = *(const uint4*)(Sw + sr * 256 + ((cc * 16) ^ ((sr & 7) << 4)));
    *(uint4*)(Opart + ((size_t)ch * NS + s0 + w * 16 + sr) * SD + hoff + cc * 8) = v;
  }
}

// ---------------- combine partials: normalize, emit Hattn (bf16) + inv_l ----------------
__global__ __launch_bounds__(256) void k_combine(const float* __restrict__ psum_part,
                                                 const bf16* __restrict__ Opart,
                                                 bf16* __restrict__ Hat, float* __restrict__ inv_l) {
  __shared__ float il_s[NH];
  const int row = blockIdx.x, t = threadIdx.x;
  if (t < NH) {
    float s = 0.f;
#pragma unroll
    for (int ch = 0; ch < CSPLIT; ch++) s += psum_part[((size_t)ch * NS + row) * NH + t];
    float iv = 1.0f / s;
    il_s[t] = iv;
    inv_l[(size_t)row * NH + t] = iv;
  }
  __syncthreads();
  const int d0 = t * 4;
  float acc[4] = {0.f, 0.f, 0.f, 0.f};
#pragma unroll
  for (int ch = 0; ch < CSPLIT; ch++) {
    bf16x4 v = *(const bf16x4*)(Opart + ((size_t)ch * NS + row) * SD + d0);
#pragma unroll
    for (int j = 0; j < 4; j++) acc[j] += (float)v[j];
  }
  float iv = il_s[d0 >> 7];
  bf16 ob[4] __attribute__((aligned(8)));
#pragma unroll
  for (int j = 0; j < 4; j++) ob[j] = f2bf(acc[j] * iv);
  *(uint2*)(Hat + (size_t)row * SD + d0) = *(const uint2*)ob;
}

// ---------------- attn.mean over heads v3 ----------------
// grid (NC/64, NS/64); 4 waves = 2x2 over (s64, c64); per-head K/Q tiles staged
// with reg prefetch; inv_l hoisted to LDS; bf16 gate.
__global__ __launch_bounds__(256) void k_mean2(const bf16* __restrict__ Q, const bf16* __restrict__ Km,
                                               const bf16* __restrict__ Gb, const float* __restrict__ inv_l,
                                               float* __restrict__ out_mean) {
  __shared__ bf16 Klm[64 * 128];
  __shared__ bf16 Qlm[64 * 128];
  __shared__ float ilv_s[64][NH];
  const int tid = threadIdx.x;
  const int l = tid & 63, w = tid >> 6;
  const int g = l >> 4, r15 = l & 15;
  const int ws = w >> 1, wc = w & 1;
  const int c0 = blockIdx.x * 64, s0 = blockIdx.y * 64;
  const float scale = 0.08838834764831845f;
  const int swz = r15 & 7;
  char* KB = (char*)Klm;
  char* QB = (char*)Qlm;
  const int row0 = tid >> 4, sl = tid & 15;

  for (int i = tid; i < 64 * NH; i += 256)
    ilv_s[i >> 3][i & 7] = inv_l[(size_t)(s0 + (i >> 3)) * NH + (i & 7)];

  uint2 gvb[2][2];
#pragma unroll
  for (int smi = 0; smi < 2; smi++)
#pragma unroll
    for (int csub = 0; csub < 2; csub++)
      gvb[smi][csub] = *(const uint2*)(Gb + (size_t)(s0 + ws * 32 + smi * 16 + r15) * NC +
                                       c0 + wc * 32 + csub * 16 + g * 4);

  f32x4 macc[2][2] = {};
  uint4 kreg[4], qreg[4];
  auto loadh = [&](int h) {
#pragma unroll
    for (int i = 0; i < 4; i++)
      kreg[i] = *(const uint4*)(Km + (size_t)(c0 + row0 + i * 16) * SD + h * DK + sl * 8);
#pragma unroll
    for (int i = 0; i < 4; i++)
      qreg[i] = *(const uint4*)(Q + (size_t)(s0 + row0 + i * 16) * SD + h * DK + sl * 8);
  };
  loadh(0);
  for (int h = 0; h < NH; ++h) {
    __syncthreads();
#pragma unroll
    for (int i = 0; i < 4; i++) {
      int row = row0 + i * 16;
      *(uint4*)(KB + row * 256 + ((sl ^ (row & 7)) << 4)) = kreg[i];
    }
#pragma unroll
    for (int i = 0; i < 4; i++) {
      int row = row0 + i * 16;
      *(uint4*)(QB + row * 256 + ((sl ^ (row & 7)) << 4)) = qreg[i];
    }
    __syncthreads();
    if (h < NH - 1) loadh(h + 1);
    bf16x8 kf[2][4], qfr[2][4];
#pragma unroll
    for (int csub = 0; csub < 2; csub++)
#pragma unroll
      for (int kk = 0; kk < 4; kk++)
        kf[csub][kk] = *(const bf16x8*)(KB + (wc * 32 + csub * 16 + r15) * 256 + (((kk * 4 + g) ^ swz) << 4));
#pragma unroll
    for (int smi = 0; smi < 2; smi++)
#pragma unroll
      for (int kk = 0; kk < 4; kk++)
        qfr[smi][kk] = *(const bf16x8*)(QB + (ws * 32 + smi * 16 + r15) * 256 + (((kk * 4 + g) ^ swz) << 4));
    float ilv[2];
#pragma unroll
    for (int smi = 0; smi < 2; smi++)
      ilv[smi] = ilv_s[ws * 32 + smi * 16 + r15][h];
#pragma unroll
    for (int smi = 0; smi < 2; smi++)
#pragma unroll
      for (int csub = 0; csub < 2; csub++) {
        f32x4 a = {0.f, 0.f, 0.f, 0.f};
#pragma unroll
        for (int kk = 0; kk < 4; kk++) a = mfma16(kf[csub][kk], qfr[smi][kk], a);
        bf16x4 gb4 = __builtin_bit_cast(bf16x4, gvb[smi][csub]);
        macc[smi][csub][0] += __expf(a[0] * scale * (float)gb4[0]) * ilv[smi];
        macc[smi][csub][1] += __expf(a[1] * scale * (float)gb4[1]) * ilv[smi];
        macc[smi][csub][2] += __expf(a[2] * scale * (float)gb4[2]) * ilv[smi];
        macc[smi][csub][3] += __expf(a[3] * scale * (float)gb4[3]) * ilv[smi];
      }
  }
#pragma unroll
  for (int smi = 0; smi < 2; smi++)
#pragma unroll
    for (int csub = 0; csub < 2; csub++) {
      int srow = s0 + ws * 32 + smi * 16 + r15;
      float4 o;
      o.x = macc[smi][csub][0] * 0.125f;
      o.y = macc[smi][csub][1] * 0.125f;
      o.z = macc[smi][csub][2] * 0.125f;
      o.w = macc[smi][csub][3] * 0.125f;
      *(float4*)(out_mean + (size_t)srow * NC + c0 + wc * 32 + csub * 16 + g * 4) = o;
    }
}

// ---------------- residual + LayerNorm ----------------
__global__ __launch_bounds__(256) void k_ln(const float* __restrict__ Op, const float* __restrict__ HS,
                                            const float* __restrict__ bO, const float* __restrict__ gamma,
                                            const float* __restrict__ beta, float* __restrict__ out) {
  __shared__ float rs[4][2];
  const int row = blockIdx.x, t = threadIdx.x;
  const int l = t & 63, w = t >> 6;
  float4 xo = *(const float4*)(Op + (size_t)row * SD + t * 4);
  float4 hs = *(const float4*)(HS + (size_t)row * SD + t * 4);
  float4 bo = *(const float4*)(bO + t * 4);
  float x[4] = {xo.x + hs.x + bo.x, xo.y + hs.y + bo.y,
                xo.z + hs.z + bo.z, xo.w + hs.w + bo.w};
  float s = x[0] + x[1] + x[2] + x[3];
  float q = x[0] * x[0] + x[1] * x[1] + x[2] * x[2] + x[3] * x[3];
#pragma unroll
  for (int m = 1; m < 64; m <<= 1) { s += __shfl_xor(s, m); q += __shfl_xor(q, m); }
  if (l == 0) { rs[w][0] = s; rs[w][1] = q; }
  __syncthreads();
  s = rs[0][0] + rs[1][0] + rs[2][0] + rs[3][0];
  q = rs[0][1] + rs[1][1] + rs[2][1] + rs[3][1];
  float mean = s * (1.0f / SD);
  float var = q * (1.0f / SD) - mean * mean;
  float rstd = rsqrtf(var + 1e-5f);
  float4 gm = *(const float4*)(gamma + t * 4);
  float4 bt = *(const float4*)(beta + t * 4);
  float4 o;
  o.x = (x[0] - mean) * rstd * gm.x + bt.x;
  o.y = (x[1] - mean) * rstd * gm.y + bt.y;
  o.z = (x[2] - mean) * rstd * gm.z + bt.z;
  o.w = (x[3] - mean) * rstd * gm.w + bt.w;
  *(float4*)(out + (size_t)row * SD + t * 4) = o;
}

extern "C" void kernel_launch(void* const* d_in, const int* in_sizes, int n_in,
                              void* d_out, int out_size, void* d_ws, size_t ws_size,
                              hipStream_t stream) {
  const float* H_S = (const float*)d_in[0];
  const float* H_C = (const float*)d_in[1];
  const float* G   = (const float*)d_in[2];
  const float* W_Q = (const float*)d_in[3];
  const float* W_K = (const float*)d_in[4];
  const float* W_V = (const float*)d_in[5];
  const float* W_O = (const float*)d_in[6];
  const float* b_O = (const float*)d_in[7];
  const float* gam = (const float*)d_in[8];
  const float* bet = (const float*)d_in[9];
  float* out = (float*)d_out;                  // (NS, SD)
  float* out_mean = out + (size_t)NS * SD;     // (NS, NC)

  char* p = (char*)d_ws;
  auto alloc = [&](size_t bytes) { char* r = p; p += (bytes + 255) & ~(size_t)255; return r; };
  // region0: staging buffers dead after QKV gemms + transpose; Opart aliases it.
  char* region0 = alloc((size_t)20 << 20);
  bf16* HSb = (bf16*)region0;                          // 4 MB
  bf16* HCb = (bf16*)(region0 + ((size_t)4 << 20));    // 4 MB
  bf16* WQb = (bf16*)(region0 + ((size_t)8 << 20));    // 2 MB
  bf16* WKb = (bf16*)(region0 + ((size_t)10 << 20));   // 1 MB
  bf16* WVb = (bf16*)(region0 + ((size_t)11 << 20));   // 1 MB
  bf16* Vb  = (bf16*)(region0 + ((size_t)12 << 20));   // 8 MB (NC x SD)
  bf16* Opart = (bf16*)region0;                        // 16 MB: CSPLIT x NS x SD bf16
  bf16* WOb = (bf16*)alloc((size_t)SD * SD * 2);
  bf16* Qb  = (bf16*)alloc((size_t)NS * SD * 2);
  bf16* Kb  = (bf16*)alloc((size_t)NC * SD * 2);
  bf16* Vtb = (bf16*)alloc((size_t)SD * NC * 2);
  bf16* Hat = (bf16*)alloc((size_t)NS * SD * 2);
  float* Opj = (float*)alloc((size_t)NS * SD * 4);
  float* invl = (float*)alloc((size_t)NS * NH * 4);
  float* psum_part = (float*)alloc((size_t)CSPLIT * NS * NH * 4);
  bf16* Gb = (bf16*)alloc((size_t)NS * NC * 2);        // 16.8 MB

  k_cast_all<<<2048, 256, 0, stream>>>(H_S, H_C, W_Q, W_K, W_V, W_O, G,
                                       HSb, HCb, WQb, WKb, WVb, WOb, Gb);

  k_gemm64<bf16><<<dim3(SD / 64, NS / 64), 256, 0, stream>>>(HSb, WQb, Qb, NS, SD, SD);
  k_gemm64<bf16><<<dim3(SD / 64, NC / 64), 256, 0, stream>>>(HCb, WKb, Kb, NC, SD, BD);
  k_gemm64<bf16><<<dim3(SD / 64, NC / 64), 256, 0, stream>>>(HCb, WVb, Vb, NC, SD, BD);
  k_transpose<<<dim3(SD / 32, NC / 32), 256, 0, stream>>>(Vb, Vtb);

  k_attn3<<<dim3(NS / 64, NH, CSPLIT), 256, 0, stream>>>(Qb, Kb, Vtb, Gb, psum_part, Opart);
  k_combine<<<NS, 256, 0, stream>>>(psum_part, Opart, Hat, invl);
  k_mean2<<<dim3(NC / 64, NS / 64), 256, 0, stream>>>(Qb, Kb, Gb, invl, out_mean);

  k_gemm64<float><<<dim3(SD / 64, NS / 64), 256, 0, stream>>>(Hat, WOb, Opj, NS, SD, SD);
  k_ln<<<NS, 256, 0, stream>>>(Opj, H_S, b_O, gam, bet, out);
}